// Round 15
// baseline (89.106 us; speedup 1.0000x reference)
//
#include <hip/hip_runtime.h>
#include <hip/hip_bf16.h>

// Problem constants: B=4, G=3, p=16, N=256, C=768, H=12, D=64
#define Bc 4
#define Gc 3
#define Nc 256
#define Cc_ 768
#define Dc 64
#define Mrows (Bc*Gc*Nc)      // 3072 tokens
#define QKVc (3*Cc_)          // 2304 fused output cols: [q | k | v]
#define Koff Cc_              // k starts at col 768
#define Voff (2*Cc_)          // v starts at col 1536

typedef _Float16 half_t;
typedef __attribute__((ext_vector_type(8))) _Float16 f16x8;
typedef __attribute__((ext_vector_type(4))) _Float16 f16x4;
typedef __attribute__((ext_vector_type(4))) float f32x4;

#define XN   (Mrows*Cc_)      // 2359296
#define WQN  (Cc_*Cc_)        // 589824
#define WKVN (2*Cc_*Cc_)      // 1179648
#define PWN  (Cc_*Cc_)        // 589824

// ---------------------------------------------------------------------------
// fp32 -> f16 conversion for x + all three weight matrices, one launch.
// wq16/wkv16 are written CONTIGUOUSLY so they form one (2304,768) weight.
// (round-6 verbatim)
// ---------------------------------------------------------------------------
__global__ __launch_bounds__(256) void cvt_all(
    const float* __restrict__ x, const float* __restrict__ wq,
    const float* __restrict__ wkv, const float* __restrict__ pw,
    half_t* __restrict__ x16, half_t* __restrict__ wq16,
    half_t* __restrict__ wkv16, half_t* __restrict__ pw16)
{
    const size_t e = ((size_t)blockIdx.x * 256 + threadIdx.x) * 8;
    const float* s; half_t* d;
    if (e < XN)                    { s = x   + e;                     d = x16   + e; }
    else if (e < XN + WQN)         { s = wq  + (e - XN);              d = wq16  + (e - XN); }
    else if (e < XN + WQN + WKVN)  { s = wkv + (e - XN - WQN);        d = wkv16 + (e - XN - WQN); }
    else                           { s = pw  + (e - XN - WQN - WKVN); d = pw16  + (e - XN - WQN - WKVN); }
    const float4 a = *(const float4*)s;
    const float4 b = *(const float4*)(s + 4);
    f16x8 o;
    o[0] = (half_t)a.x; o[1] = (half_t)a.y; o[2] = (half_t)a.z; o[3] = (half_t)a.w;
    o[4] = (half_t)b.x; o[5] = (half_t)b.y; o[6] = (half_t)b.z; o[7] = (half_t)b.w;
    *(f16x8*)d = o;
}

// ---------------------------------------------------------------------------
// f16 MFMA GEMM (round-6 structure; r14 epilogue change ONLY):
// C[m][n] = sum_k A[m][k]*W[n][k]  (+ bias[n])
// 128x128 tile, BK=32, 256 thr = 4 waves (2x2 of 64x64), mfma 16x16x32.
// Staging/pipeline verbatim from r6 (known-good 85.5us base).
//
// r14: MFMA operands SWAPPED — mfma(bf, af) — so the C/D fragment layout
// becomes: arg1(af)-row m -> lane&15 (fixed per lane), arg0(bf)-row n ->
// (lane>>4)*4 + reg (4 CONSECUTIVE columns per lane). The epilogue then
// stores one f16x4 (8B) / float4 (16B) per fragment instead of 4 scalar
// column-strided stores: 64 -> 16 store instrs/thread, zero added ALU.
// (Old layout per m89: arg0-row -> (lane>>4)*4+reg, arg1-row -> lane&15;
// swap verified from the same mapping that the r6 epilogue used.)
// Failed perturbations (do not retry): TM=64 tile (r7 +6.4us), setprio
// (r7, lockstep = m190 regime), reg-staging cvt-in-GEMM (r9, +34us),
// persistent fusion (r11, +159us), XCD tile swizzle (r12, +10us).
// ---------------------------------------------------------------------------
template<typename OutT, bool BIAS>
__global__ __launch_bounds__(256) void gemm16(
    const half_t* __restrict__ A, const half_t* __restrict__ W,
    OutT* __restrict__ C, const float* __restrict__ bias,
    int M, int Nn, int K)
{
    // [buf][A/B][kgroup][row][8 f16] = 48 KiB
    __shared__ __attribute__((aligned(16))) half_t sm[3][2][4][128][8];

    const int tid = threadIdx.x;
    const int w   = tid >> 6;          // wave 0..3
    const int l   = tid & 63;
    const int wm  = w >> 1;            // m sub-tile
    const int wn  = w & 1;             // n sub-tile
    const int m0  = blockIdx.y << 7;
    const int n0  = blockIdx.x << 7;

    f32x4 acc[4][4] = {};

    // stage one 128x32 A-tile + B-tile: 4 global_load_lds(16B) per thread
    auto stage = [&](int buf, int k0) {
        #pragma unroll
        for (int i = 0; i < 2; ++i) {
            const int c   = w * 2 + i;
            const int kg  = c >> 1;
            const int r0  = (c & 1) * 64;
            const half_t* ga = A + (size_t)(m0 + r0 + l) * K + k0 + kg * 8;
            const half_t* gb = W + (size_t)(n0 + r0 + l) * K + k0 + kg * 8;
            __builtin_amdgcn_global_load_lds(
                (__attribute__((address_space(1))) void*)ga,
                (__attribute__((address_space(3))) void*)&sm[buf][0][kg][r0][0],
                16, 0, 0);
            __builtin_amdgcn_global_load_lds(
                (__attribute__((address_space(1))) void*)gb,
                (__attribute__((address_space(3))) void*)&sm[buf][1][kg][r0][0],
                16, 0, 0);
        }
    };

    const int NT = K >> 5;             // 24 for K=768 (always >= 2 here)
    stage(0, 0);
    stage(1, 32);

    const int kg = l >> 4;             // 0..3
    const int lr = l & 15;
    int cur = 0;

    for (int t = 0; t < NT; ++t) {
        // retire exactly stage(t) (own wave), allow stage(t+1) in flight
        if (t + 1 < NT) asm volatile("s_waitcnt vmcnt(4)" ::: "memory");
        else            asm volatile("s_waitcnt vmcnt(0)" ::: "memory");
        __builtin_amdgcn_s_barrier();
        if (t + 2 < NT) {
            int nb = cur + 2; if (nb >= 3) nb -= 3;
            stage(nb, (t + 2) << 5);
        }

        f16x8 af[4], bf[4];
        #pragma unroll
        for (int mi = 0; mi < 4; ++mi)
            af[mi] = *(const f16x8*)&sm[cur][0][kg][wm * 64 + mi * 16 + lr][0];
        #pragma unroll
        for (int ni = 0; ni < 4; ++ni)
            bf[ni] = *(const f16x8*)&sm[cur][1][kg][wn * 64 + ni * 16 + lr][0];

        #pragma unroll
        for (int mi = 0; mi < 4; ++mi)
            #pragma unroll
            for (int ni = 0; ni < 4; ++ni)
                acc[mi][ni] = __builtin_amdgcn_mfma_f32_16x16x32_f16(
                    bf[ni], af[mi], acc[mi][ni], 0, 0, 0);   // r14: swapped

        cur = (cur == 2) ? 0 : cur + 1;
    }

    // r14 epilogue: lane holds row m = ...+lr (fixed), cols n = gcol0 + r
    // (4 consecutive) -> one vector store per fragment, 16 stores/thread.
    const int lq = l >> 4;
    #pragma unroll
    for (int mi = 0; mi < 4; ++mi) {
        const int grow = m0 + wm * 64 + mi * 16 + lr;
        #pragma unroll
        for (int ni = 0; ni < 4; ++ni) {
            const int gcol0 = n0 + wn * 64 + ni * 16 + lq * 4;
            float v0 = acc[mi][ni][0], v1 = acc[mi][ni][1];
            float v2 = acc[mi][ni][2], v3 = acc[mi][ni][3];
            if constexpr (BIAS) {
                const float4 bv = *(const float4*)&bias[gcol0];
                v0 += bv.x; v1 += bv.y; v2 += bv.z; v3 += bv.w;
            }
            if constexpr (sizeof(OutT) == 4) {
                float4 rv; rv.x = v0; rv.y = v1; rv.z = v2; rv.w = v3;
                *(float4*)&C[(size_t)grow * Nn + gcol0] = rv;       // 16B
            } else {
                f16x4 hv;
                hv[0] = (half_t)v0; hv[1] = (half_t)v1;
                hv[2] = (half_t)v2; hv[3] = (half_t)v3;
                *(f16x4*)&C[(size_t)grow * Nn + gcol0] = hv;        // 8B
            }
        }
    }
}

// ---------------------------------------------------------------------------
// Attention (round-6 verbatim): one block (4 waves) per token t=(g*B+b)*N+n;
// wave handles heads {w, w+4, w+8}. Q/K/V from the fused QKV buffer (f16,
// fp32 math); K/V gathered via the triplane map.
// Failed perturbations (do not retry): head-interleaved ILP (r8, +1.7us),
// token->XCD swizzle (r12), 256-block persistent form (r11).
// ---------------------------------------------------------------------------
__global__ __launch_bounds__(256) void attn_kernel(
    const half_t* __restrict__ QKV,  // (Mrows, 2304) f16 x-order; [q|k|v]
    half_t* __restrict__ Oa)         // (Mrows, C) f16, out-order rows (g,b,n)
{
    const int t  = blockIdx.x;
    const int g  = t >> 10;
    const int b  = (t >> 8) & 3;
    const int n  = t & 255;
    const int a  = n >> 4;
    const int bc = n & 15;

    __shared__ float qs[Cc_];
    __shared__ int   rows[32];

    const int qrow = (b * Gc + g) * Nc + n;
    if (threadIdx.x < 96) {
        const f16x8 v = ((const f16x8*)(QKV + (size_t)qrow * QKVc))[threadIdx.x];
        #pragma unroll
        for (int jj = 0; jj < 8; ++jj) qs[threadIdx.x * 8 + jj] = (float)v[jj];
    }
    if (threadIdx.x < 32) {
        const int j = threadIdx.x;
        int g1 = g + 1; if (g1 >= 3) g1 -= 3;
        int g2 = g + 2; if (g2 >= 3) g2 -= 3;
        rows[j] = (j < 16) ? ((b * Gc + g1) * Nc + a * 16 + j)
                           : ((b * Gc + g2) * Nc + (j - 16) * 16 + bc);
    }
    __syncthreads();

    const int wave = threadIdx.x >> 6;
    const int lane = threadIdx.x & 63;
    const int j    = lane & 31;
    const int dh   = lane >> 5;
    const size_t kvrow = (size_t)rows[j] * QKVc;

    for (int hh = 0; hh < 3; ++hh) {
        const int h = wave + hh * 4;
        // ---- scores: lane=(j ctx, dh half), vectorized f16 K reads ----
        const f16x8* kp = (const f16x8*)(QKV + kvrow + Koff + h * Dc + dh * 32);
        const float* qp = qs + h * Dc + dh * 32;
        float s = 0.f;
        #pragma unroll
        for (int c = 0; c < 4; ++c) {
            const f16x8 k8 = kp[c];
            #pragma unroll
            for (int e = 0; e < 8; ++e) s = fmaf(qp[c * 8 + e], (float)k8[e], s);
        }
        s += __shfl_xor(s, 32);
        s *= 0.125f;                         // 1/sqrt(64)

        // ---- softmax over 32 ctx (halves identical) ----
        float m = s;
        #pragma unroll
        for (int off = 16; off >= 1; off >>= 1) m = fmaxf(m, __shfl_xor(m, off));
        const float e = __expf(s - m);
        float lsum = e;
        #pragma unroll
        for (int off = 16; off >= 1; off >>= 1) lsum += __shfl_xor(lsum, off);
        const float pr = e / lsum;

        // ---- PV: lane = output dim ----
        float o = 0.f;
        #pragma unroll 8
        for (int jj = 0; jj < 32; ++jj) {
            const float pj = __shfl(pr, jj);
            o = fmaf(pj, (float)QKV[(size_t)rows[jj] * QKVc + Voff + h * Dc + lane], o);
        }
        Oa[(size_t)t * Cc_ + h * Dc + lane] = (half_t)o;
    }
}

extern "C" void kernel_launch(void* const* d_in, const int* in_sizes, int n_in,
                              void* d_out, int out_size, void* d_ws, size_t ws_size,
                              hipStream_t stream) {
    const float* x   = (const float*)d_in[0];
    const float* wq  = (const float*)d_in[1];
    const float* wkv = (const float*)d_in[2];
    const float* pw  = (const float*)d_in[3];
    const float* pb  = (const float*)d_in[4];
    float* out = (float*)d_out;

    // f16 workspace (~19 MB used)
    half_t* x16   = (half_t*)d_ws;
    half_t* w3    = x16 + XN;                      // [wq; wkv] = (2304, 768)
    half_t* pw16  = w3 + WQN + WKVN;
    half_t* QKV16 = pw16 + PWN;                    // (3072, 2304)
    half_t* ATT16 = QKV16 + (size_t)Mrows * QKVc;  // (3072, 768)

    const dim3 blk(256);

    // 1. fp32 -> f16 (x + weights); wq/wkv land contiguously in w3
    cvt_all<<<dim3((XN + WQN + WKVN + PWN) / 8 / 256), blk, 0, stream>>>(
        x, wq, wkv, pw, x16, w3, w3 + WQN, pw16);

    // 2. QKV = x16 @ [wq;wkv]^T — one fused GEMM (3072 x 2304 x 768)
    gemm16<half_t, false><<<dim3(QKVc / 128, Mrows / 128), blk, 0, stream>>>(
        x16, w3, QKV16, nullptr, Mrows, QKVc, Cc_);

    // 3. attention with gathered K/V, writes out-order rows (f16)
    attn_kernel<<<dim3(Mrows), blk, 0, stream>>>(QKV16, ATT16);

    // 4. out = ATT16 @ pw16^T + pb  (fp32 epilogue straight into d_out)
    gemm16<float, true><<<dim3(Cc_ / 128, Mrows / 128), blk, 0, stream>>>(
        ATT16, pw16, out, pb, Mrows, Cc_, Cc_);
}

// Round 16
// 85.536 us; speedup vs baseline: 1.0417x; 1.0417x over previous
//
#include <hip/hip_runtime.h>
#include <hip/hip_bf16.h>

// Problem constants: B=4, G=3, p=16, N=256, C=768, H=12, D=64
#define Bc 4
#define Gc 3
#define Nc 256
#define Cc_ 768
#define Dc 64
#define Mrows (Bc*Gc*Nc)      // 3072 tokens
#define QKVc (3*Cc_)          // 2304 fused output cols: [q | k | v]
#define Koff Cc_              // k starts at col 768
#define Voff (2*Cc_)          // v starts at col 1536

typedef _Float16 half_t;
typedef __attribute__((ext_vector_type(8))) _Float16 f16x8;
typedef __attribute__((ext_vector_type(4))) float f32x4;

#define XN   (Mrows*Cc_)      // 2359296
#define WQN  (Cc_*Cc_)        // 589824
#define WKVN (2*Cc_*Cc_)      // 1179648
#define PWN  (Cc_*Cc_)        // 589824

// ---------------------------------------------------------------------------
// FINAL KERNEL (r6 structure, twice-measured 85.5/85.7us, A/A noise ±0.2us).
// Complete failed-perturbation ledger (all vs this baseline, all real signal):
//   r7  TM=64 proj tile + setprio        +6.4us  (occupancy theory wrong;
//                                                 lockstep = m190 null regime)
//   r8  attention head-interleaved ILP   +1.7us  (TLP already hides latency)
//   r9  reg-staged cvt-in-GEMM fusion    +34us   (m151 regression amplified)
//   r11 cooperative persistent fusion    +159us  (killed attn TLP, 1 blk/CU)
//   r12 XCD swizzle (GEMM tiles + attn)  +9.9us  (L3-resident: m160 regime)
//   r14 operand-swap vector epilogue     +3.4us  (store tail already hidden)
// Structural constraint: small-problem plateau — 4-dispatch pipeline with
// per-phase-matched grids; 8-phase/256-tile GEMM ladder needs >=4x the tile
// count to occupy 256 CUs. Remaining gap vs ~50us pure kernel work is
// dispatch/ramp overhead proven non-removable at this size (r9-r11).
// ---------------------------------------------------------------------------

// fp32 -> f16 conversion for x + all three weight matrices, one launch.
// wq16/wkv16 are written CONTIGUOUSLY so they form one (2304,768) weight.
__global__ __launch_bounds__(256) void cvt_all(
    const float* __restrict__ x, const float* __restrict__ wq,
    const float* __restrict__ wkv, const float* __restrict__ pw,
    half_t* __restrict__ x16, half_t* __restrict__ wq16,
    half_t* __restrict__ wkv16, half_t* __restrict__ pw16)
{
    const size_t e = ((size_t)blockIdx.x * 256 + threadIdx.x) * 8;
    const float* s; half_t* d;
    if (e < XN)                    { s = x   + e;                     d = x16   + e; }
    else if (e < XN + WQN)         { s = wq  + (e - XN);              d = wq16  + (e - XN); }
    else if (e < XN + WQN + WKVN)  { s = wkv + (e - XN - WQN);        d = wkv16 + (e - XN - WQN); }
    else                           { s = pw  + (e - XN - WQN - WKVN); d = pw16  + (e - XN - WQN - WKVN); }
    const float4 a = *(const float4*)s;
    const float4 b = *(const float4*)(s + 4);
    f16x8 o;
    o[0] = (half_t)a.x; o[1] = (half_t)a.y; o[2] = (half_t)a.z; o[3] = (half_t)a.w;
    o[4] = (half_t)b.x; o[5] = (half_t)b.y; o[6] = (half_t)b.z; o[7] = (half_t)b.w;
    *(f16x8*)d = o;
}

// f16 MFMA GEMM: C[m][n] = sum_k A[m][k]*W[n][k] (+ bias[n])
// 128x128 tile, BK=32, 256 thr = 4 waves (2x2 of 64x64), mfma 16x16x32.
// T3/T4-lite: 3 LDS buffers, stage 2 tiles ahead via global_load_lds(16B),
// counted `s_waitcnt vmcnt(4)` + raw s_barrier — never drains vmcnt(0) in
// the main loop. Stage(t+2) issued AFTER the barrier: between barriers waves
// read buf[t%3] and write buf[(t+2)%3] only.
template<typename OutT, bool BIAS>
__global__ __launch_bounds__(256) void gemm16(
    const half_t* __restrict__ A, const half_t* __restrict__ W,
    OutT* __restrict__ C, const float* __restrict__ bias,
    int M, int Nn, int K)
{
    // [buf][A/B][kgroup][row][8 f16] = 48 KiB
    __shared__ __attribute__((aligned(16))) half_t sm[3][2][4][128][8];

    const int tid = threadIdx.x;
    const int w   = tid >> 6;          // wave 0..3
    const int l   = tid & 63;
    const int wm  = w >> 1;            // m sub-tile
    const int wn  = w & 1;             // n sub-tile
    const int m0  = blockIdx.y << 7;
    const int n0  = blockIdx.x << 7;

    f32x4 acc[4][4] = {};

    // stage one 128x32 A-tile + B-tile: 4 global_load_lds(16B) per thread
    auto stage = [&](int buf, int k0) {
        #pragma unroll
        for (int i = 0; i < 2; ++i) {
            const int c   = w * 2 + i;
            const int kg  = c >> 1;
            const int r0  = (c & 1) * 64;
            const half_t* ga = A + (size_t)(m0 + r0 + l) * K + k0 + kg * 8;
            const half_t* gb = W + (size_t)(n0 + r0 + l) * K + k0 + kg * 8;
            __builtin_amdgcn_global_load_lds(
                (__attribute__((address_space(1))) void*)ga,
                (__attribute__((address_space(3))) void*)&sm[buf][0][kg][r0][0],
                16, 0, 0);
            __builtin_amdgcn_global_load_lds(
                (__attribute__((address_space(1))) void*)gb,
                (__attribute__((address_space(3))) void*)&sm[buf][1][kg][r0][0],
                16, 0, 0);
        }
    };

    const int NT = K >> 5;             // 24 for K=768 (always >= 2 here)
    stage(0, 0);
    stage(1, 32);

    const int kg = l >> 4;             // 0..3
    const int lr = l & 15;
    int cur = 0;

    for (int t = 0; t < NT; ++t) {
        // retire exactly stage(t) (own wave), allow stage(t+1) in flight
        if (t + 1 < NT) asm volatile("s_waitcnt vmcnt(4)" ::: "memory");
        else            asm volatile("s_waitcnt vmcnt(0)" ::: "memory");
        __builtin_amdgcn_s_barrier();
        if (t + 2 < NT) {
            int nb = cur + 2; if (nb >= 3) nb -= 3;
            stage(nb, (t + 2) << 5);
        }

        f16x8 af[4], bf[4];
        #pragma unroll
        for (int mi = 0; mi < 4; ++mi)
            af[mi] = *(const f16x8*)&sm[cur][0][kg][wm * 64 + mi * 16 + lr][0];
        #pragma unroll
        for (int ni = 0; ni < 4; ++ni)
            bf[ni] = *(const f16x8*)&sm[cur][1][kg][wn * 64 + ni * 16 + lr][0];

        #pragma unroll
        for (int mi = 0; mi < 4; ++mi)
            #pragma unroll
            for (int ni = 0; ni < 4; ++ni)
                acc[mi][ni] = __builtin_amdgcn_mfma_f32_16x16x32_f16(
                    af[mi], bf[ni], acc[mi][ni], 0, 0, 0);

        cur = (cur == 2) ? 0 : cur + 1;
    }

    // epilogue: C/D layout col = lane&15, row = (lane>>4)*4 + reg (m89)
    const int lq = l >> 4;
    #pragma unroll
    for (int ni = 0; ni < 4; ++ni) {
        const int gcol = n0 + wn * 64 + ni * 16 + lr;
        const float bv = BIAS ? bias[gcol] : 0.f;
        #pragma unroll
        for (int mi = 0; mi < 4; ++mi) {
            const int grow = m0 + wm * 64 + mi * 16 + lq * 4;
            #pragma unroll
            for (int r = 0; r < 4; ++r)
                C[(size_t)(grow + r) * Nn + gcol] = (OutT)(acc[mi][ni][r] + bv);
        }
    }
}

// Attention: one block (4 waves) per token t=(g*B+b)*N+n; wave handles heads
// {w, w+4, w+8}. Q/K/V from the fused QKV buffer (f16, fp32 math); K/V
// gathered via the triplane map. 3072-block TLP hides all gather latency.
__global__ __launch_bounds__(256) void attn_kernel(
    const half_t* __restrict__ QKV,  // (Mrows, 2304) f16 x-order; [q|k|v]
    half_t* __restrict__ Oa)         // (Mrows, C) f16, out-order rows (g,b,n)
{
    const int t  = blockIdx.x;
    const int g  = t >> 10;
    const int b  = (t >> 8) & 3;
    const int n  = t & 255;
    const int a  = n >> 4;
    const int bc = n & 15;

    __shared__ float qs[Cc_];
    __shared__ int   rows[32];

    const int qrow = (b * Gc + g) * Nc + n;
    if (threadIdx.x < 96) {
        const f16x8 v = ((const f16x8*)(QKV + (size_t)qrow * QKVc))[threadIdx.x];
        #pragma unroll
        for (int jj = 0; jj < 8; ++jj) qs[threadIdx.x * 8 + jj] = (float)v[jj];
    }
    if (threadIdx.x < 32) {
        const int j = threadIdx.x;
        int g1 = g + 1; if (g1 >= 3) g1 -= 3;
        int g2 = g + 2; if (g2 >= 3) g2 -= 3;
        rows[j] = (j < 16) ? ((b * Gc + g1) * Nc + a * 16 + j)
                           : ((b * Gc + g2) * Nc + (j - 16) * 16 + bc);
    }
    __syncthreads();

    const int wave = threadIdx.x >> 6;
    const int lane = threadIdx.x & 63;
    const int j    = lane & 31;
    const int dh   = lane >> 5;
    const size_t kvrow = (size_t)rows[j] * QKVc;

    for (int hh = 0; hh < 3; ++hh) {
        const int h = wave + hh * 4;
        // ---- scores: lane=(j ctx, dh half), vectorized f16 K reads ----
        const f16x8* kp = (const f16x8*)(QKV + kvrow + Koff + h * Dc + dh * 32);
        const float* qp = qs + h * Dc + dh * 32;
        float s = 0.f;
        #pragma unroll
        for (int c = 0; c < 4; ++c) {
            const f16x8 k8 = kp[c];
            #pragma unroll
            for (int e = 0; e < 8; ++e) s = fmaf(qp[c * 8 + e], (float)k8[e], s);
        }
        s += __shfl_xor(s, 32);
        s *= 0.125f;                         // 1/sqrt(64)

        // ---- softmax over 32 ctx (halves identical) ----
        float m = s;
        #pragma unroll
        for (int off = 16; off >= 1; off >>= 1) m = fmaxf(m, __shfl_xor(m, off));
        const float e = __expf(s - m);
        float lsum = e;
        #pragma unroll
        for (int off = 16; off >= 1; off >>= 1) lsum += __shfl_xor(lsum, off);
        const float pr = e / lsum;

        // ---- PV: lane = output dim ----
        float o = 0.f;
        #pragma unroll 8
        for (int jj = 0; jj < 32; ++jj) {
            const float pj = __shfl(pr, jj);
            o = fmaf(pj, (float)QKV[(size_t)rows[jj] * QKVc + Voff + h * Dc + lane], o);
        }
        Oa[(size_t)t * Cc_ + h * Dc + lane] = (half_t)o;
    }
}

extern "C" void kernel_launch(void* const* d_in, const int* in_sizes, int n_in,
                              void* d_out, int out_size, void* d_ws, size_t ws_size,
                              hipStream_t stream) {
    const float* x   = (const float*)d_in[0];
    const float* wq  = (const float*)d_in[1];
    const float* wkv = (const float*)d_in[2];
    const float* pw  = (const float*)d_in[3];
    const float* pb  = (const float*)d_in[4];
    float* out = (float*)d_out;

    // f16 workspace (~19 MB used)
    half_t* x16   = (half_t*)d_ws;
    half_t* w3    = x16 + XN;                      // [wq; wkv] = (2304, 768)
    half_t* pw16  = w3 + WQN + WKVN;
    half_t* QKV16 = pw16 + PWN;                    // (3072, 2304)
    half_t* ATT16 = QKV16 + (size_t)Mrows * QKVc;  // (3072, 768)

    const dim3 blk(256);

    // 1. fp32 -> f16 (x + weights); wq/wkv land contiguously in w3
    cvt_all<<<dim3((XN + WQN + WKVN + PWN) / 8 / 256), blk, 0, stream>>>(
        x, wq, wkv, pw, x16, w3, w3 + WQN, pw16);

    // 2. QKV = x16 @ [wq;wkv]^T — one fused GEMM (3072 x 2304 x 768)
    gemm16<half_t, false><<<dim3(QKVc / 128, Mrows / 128), blk, 0, stream>>>(
        x16, w3, QKV16, nullptr, Mrows, QKVc, Cc_);

    // 3. attention with gathered K/V, writes out-order rows (f16)
    attn_kernel<<<dim3(Mrows), blk, 0, stream>>>(QKV16, ATT16);

    // 4. out = ATT16 @ pw16^T + pb  (fp32 epilogue straight into d_out)
    gemm16<float, true><<<dim3(Cc_ / 128, Mrows / 128), blk, 0, stream>>>(
        ATT16, pw16, out, pb, Mrows, Cc_, Cc_);
}